// Round 3
// baseline (45.168 us; speedup 1.0000x reference)
//
#include <hip/hip_runtime.h>

// X,Y: [32,3,512,512] f32 reinterpreted flat as NHWC [32][512][512][3].
// loss = sum_b mean_{crop} [ filt(d^2) - filt(d)^2 ],  d = X - Y,
// filt = separable 3x3 gaussian (sigma=1.5): taps [g0, g1, g0].
// Crop [5:-5] => reflect padding never exercised.
// hc = h*3+c flat contiguous index in [0,1536); outputs hc in [15,1520].

constexpr int Wd     = 512;
constexpr int Hd     = 512;
constexpr int Cd     = 3;
constexpr int ROW    = Hd * Cd;          // 1536 floats per w-row
constexpr int CROPc  = 5;
constexpr int NOUTc  = Wd - 2 * CROPc;   // 502
constexpr int HC_LO  = 15;
constexpr int HC_HI  = 1520;

constexpr int NWIN   = 7;                // hc windows, 246 outputs each (last 30)
constexpr int OUTW   = 246;
constexpr int NCHUNK = 24;               // w chunks
constexpr int CHUNKc = 21;               // 23*21 + 19 = 502
constexpr int BLOCK  = 256;
constexpr int NWAVES = 32 * NCHUNK * NWIN;       // 5376
constexpr int NBLK   = NWAVES / (BLOCK / 64);    // 1344
static_assert(NWAVES % (BLOCK / 64) == 0, "");

__global__ __launch_bounds__(BLOCK) void locvar_kernel(
    const float* __restrict__ X,
    const float* __restrict__ Y,
    float* __restrict__ partial)
{
    const int lane = threadIdx.x & 63;
    const int widx = threadIdx.x >> 6;
    const int gw   = blockIdx.x * (BLOCK / 64) + widx;   // 0..5375

    const int win   = gw % NWIN;                 // fastest: adjacent waves adjacent in hc
    const int rest  = gw / NWIN;
    const int chunk = rest % NCHUNK;
    const int b     = rest / NCHUNK;

    const int o_lo = HC_LO + OUTW * win;
    const int o_hi = min(o_lo + OUTW - 1, HC_HI);
    const int s    = (o_lo - 3) & ~3;            // 16B-aligned window start
    const int idx0 = s + 4 * lane;               // this lane's element 0 (hc index)

    const int w0 = CROPc + chunk * CHUNKc;
    const int wn = min(CHUNKc, CROPc + NOUTc - w0);   // 21 or 19

    // per-element output masks (exclusive partition across windows)
    float4 msk;
    msk.x = (idx0 + 0 >= o_lo && idx0 + 0 <= o_hi) ? 1.0f : 0.0f;
    msk.y = (idx0 + 1 >= o_lo && idx0 + 1 <= o_hi) ? 1.0f : 0.0f;
    msk.z = (idx0 + 2 >= o_lo && idx0 + 2 <= o_hi) ? 1.0f : 0.0f;
    msk.w = (idx0 + 3 >= o_lo && idx0 + 3 <= o_hi) ? 1.0f : 0.0f;

    // gaussian taps (sigma=1.5, ksize=3); constant-folded
    const float e  = expf(-1.0f / 4.5f);
    const float g1 = 1.0f / (1.0f + 2.0f * e);
    const float g0 = e * g1;

    const int am = ((lane - 1) & 63) << 2;   // prev-lane bpermute addr
    const int ap = ((lane + 1) & 63) << 2;   // next-lane bpermute addr

    const size_t base = (size_t)b * Wd * ROW + (size_t)idx0;

#define BPERM(A, V) __int_as_float(__builtin_amdgcn_ds_bpermute((A), __float_as_int(V)))

    // One w-row: 2 float4 loads, 6 bpermutes, rowsum R (filt_h of d) and Q (filt_h of d^2)
#define ROWSUMS(OFF, Rr, Qq)                                                   \
    {                                                                          \
        float4 x4 = *reinterpret_cast<const float4*>(X + (OFF));               \
        float4 y4 = *reinterpret_cast<const float4*>(Y + (OFF));               \
        float4 d;                                                              \
        d.x = x4.x - y4.x; d.y = x4.y - y4.y;                                  \
        d.z = x4.z - y4.z; d.w = x4.w - y4.w;                                  \
        float pm1 = BPERM(am, d.y), pm2 = BPERM(am, d.z), pm3 = BPERM(am, d.w);\
        float np0 = BPERM(ap, d.x), np1 = BPERM(ap, d.y), np2 = BPERM(ap, d.z);\
        float4 dm, dp;                                                         \
        dm.x = pm1; dm.y = pm2; dm.z = pm3; dm.w = d.x;                        \
        dp.x = d.w; dp.y = np0; dp.z = np1; dp.w = np2;                        \
        Rr.x = fmaf(g0, dm.x + dp.x, g1 * d.x);                                \
        Rr.y = fmaf(g0, dm.y + dp.y, g1 * d.y);                                \
        Rr.z = fmaf(g0, dm.z + dp.z, g1 * d.z);                                \
        Rr.w = fmaf(g0, dm.w + dp.w, g1 * d.w);                                \
        Qq.x = fmaf(g0, fmaf(dp.x, dp.x, dm.x * dm.x), g1 * (d.x * d.x));      \
        Qq.y = fmaf(g0, fmaf(dp.y, dp.y, dm.y * dm.y), g1 * (d.y * d.y));      \
        Qq.z = fmaf(g0, fmaf(dp.z, dp.z, dm.z * dm.z), g1 * (d.z * d.z));      \
        Qq.w = fmaf(g0, fmaf(dp.w, dp.w, dm.w * dm.w), g1 * (d.w * d.w));      \
    }

    float4 R0, R1, Q0, Q1;
    {
        size_t off = base + (size_t)(w0 - 1) * ROW;
        ROWSUMS(off, R0, Q0);
        off += ROW;
        ROWSUMS(off, R1, Q1);
    }

    float4 acc = {0.0f, 0.0f, 0.0f, 0.0f};
    size_t off = base + (size_t)(w0 + 1) * ROW;
    #pragma unroll 3
    for (int i = 0; i < wn; ++i, off += ROW) {
        float4 R2, Q2;
        ROWSUMS(off, R2, Q2);

        float4 S1, S2;
        S1.x = fmaf(g0, R0.x + R2.x, g1 * R1.x);
        S1.y = fmaf(g0, R0.y + R2.y, g1 * R1.y);
        S1.z = fmaf(g0, R0.z + R2.z, g1 * R1.z);
        S1.w = fmaf(g0, R0.w + R2.w, g1 * R1.w);
        S2.x = fmaf(g0, Q0.x + Q2.x, g1 * Q1.x);
        S2.y = fmaf(g0, Q0.y + Q2.y, g1 * Q1.y);
        S2.z = fmaf(g0, Q0.z + Q2.z, g1 * Q1.z);
        S2.w = fmaf(g0, Q0.w + Q2.w, g1 * Q1.w);

        acc.x = fmaf(msk.x, fmaf(-S1.x, S1.x, S2.x), acc.x);
        acc.y = fmaf(msk.y, fmaf(-S1.y, S1.y, S2.y), acc.y);
        acc.z = fmaf(msk.z, fmaf(-S1.z, S1.z, S2.z), acc.z);
        acc.w = fmaf(msk.w, fmaf(-S1.w, S1.w, S2.w), acc.w);

        R0 = R1; R1 = R2;
        Q0 = Q1; Q1 = Q2;
    }
#undef ROWSUMS
#undef BPERM

    float a = (acc.x + acc.y) + (acc.z + acc.w);

    // deterministic reduction: wave shuffle then LDS
    #pragma unroll
    for (int o = 32; o > 0; o >>= 1) a += __shfl_down(a, o, 64);

    __shared__ float sdata[BLOCK / 64];
    if (lane == 0) sdata[widx] = a;
    __syncthreads();
    if (threadIdx.x == 0) {
        float sum = 0.0f;
        #pragma unroll
        for (int i = 0; i < BLOCK / 64; ++i) sum += sdata[i];
        partial[blockIdx.x] = sum;
    }
}

__global__ __launch_bounds__(BLOCK) void reduce_kernel(
    const float* __restrict__ partial,
    float* __restrict__ out)
{
    float acc = 0.0f;
    for (int i = threadIdx.x; i < NBLK; i += BLOCK) acc += partial[i];

    #pragma unroll
    for (int o = 32; o > 0; o >>= 1) acc += __shfl_down(acc, o, 64);

    __shared__ float sdata[BLOCK / 64];
    const int lane = threadIdx.x & 63;
    const int wid  = threadIdx.x >> 6;
    if (lane == 0) sdata[wid] = acc;
    __syncthreads();
    if (threadIdx.x == 0) {
        float s = 0.0f;
        #pragma unroll
        for (int i = 0; i < BLOCK / 64; ++i) s += sdata[i];
        out[0] = s * (1.0f / ((float)NOUTc * (float)NOUTc * (float)Cd));
    }
}

extern "C" void kernel_launch(void* const* d_in, const int* in_sizes, int n_in,
                              void* d_out, int out_size, void* d_ws, size_t ws_size,
                              hipStream_t stream) {
    const float* X = (const float*)d_in[0];
    const float* Y = (const float*)d_in[1];
    float* out     = (float*)d_out;
    float* partial = (float*)d_ws;   // NBLK floats

    locvar_kernel<<<NBLK, BLOCK, 0, stream>>>(X, Y, partial);
    reduce_kernel<<<1, BLOCK, 0, stream>>>(partial, out);
}

// Round 4
// 44.762 us; speedup vs baseline: 1.0091x; 1.0091x over previous
//
#include <hip/hip_runtime.h>

// X,Y: [32,3,512,512] f32 reinterpreted flat as NHWC [32][512][512][3].
// loss = sum_b mean_{crop} [ filt(d^2) - filt(d)^2 ],  d = X - Y,
// filt = separable 3x3 gaussian (sigma=1.5): taps [g0, g1, g0].
// Crop [5:-5] => reflect padding never exercised.
// hc = h*3+c flat contiguous index in [0,1536); outputs hc in [15,1520].

constexpr int Wd     = 512;
constexpr int Hd     = 512;
constexpr int Cd     = 3;
constexpr int ROW    = Hd * Cd;          // 1536 floats per w-row
constexpr int CROPc  = 5;
constexpr int NOUTc  = Wd - 2 * CROPc;   // 502
constexpr int HC_LO  = 15;
constexpr int HC_HI  = 1520;

constexpr int NWIN   = 7;                // hc windows of 246 outputs (96% of 256 lanes-elems)
constexpr int OUTW   = 246;
constexpr int NCHUNK = 32;               // w chunks: 31*16 + 6 = 502
constexpr int CHUNKc = 16;
constexpr int BLOCK  = 256;
constexpr int NWAVES = 32 * NCHUNK * NWIN;       // 7168
constexpr int NBLK   = NWAVES / (BLOCK / 64);    // 1792 = exactly 7 blocks/CU
static_assert(NWAVES % (BLOCK / 64) == 0, "");

__global__ __launch_bounds__(BLOCK, 6) void locvar_kernel(
    const float* __restrict__ X,
    const float* __restrict__ Y,
    float* __restrict__ partial)
{
    const int lane = threadIdx.x & 63;
    const int widx = threadIdx.x >> 6;
    const int gw   = blockIdx.x * (BLOCK / 64) + widx;   // 0..7167

    const int win   = gw % NWIN;                 // fastest: adjacent waves adjacent in hc
    const int rest  = gw / NWIN;
    const int chunk = rest % NCHUNK;
    const int b     = rest / NCHUNK;

    const int o_lo = HC_LO + OUTW * win;
    const int o_hi = min(o_lo + OUTW - 1, HC_HI);
    const int s    = (o_lo - 3) & ~3;            // 16B-aligned window start
    const int idx0 = s + 4 * lane;               // this lane's element 0 (hc index)

    const int w0 = CROPc + chunk * CHUNKc;
    const int wn = min(CHUNKc, CROPc + NOUTc - w0);   // 16 (last chunk: 6)

    // per-element output masks (exclusive partition across windows; edge-lane
    // bpermute garbage provably lands only on masked elements)
    float4 msk;
    msk.x = (idx0 + 0 >= o_lo && idx0 + 0 <= o_hi) ? 1.0f : 0.0f;
    msk.y = (idx0 + 1 >= o_lo && idx0 + 1 <= o_hi) ? 1.0f : 0.0f;
    msk.z = (idx0 + 2 >= o_lo && idx0 + 2 <= o_hi) ? 1.0f : 0.0f;
    msk.w = (idx0 + 3 >= o_lo && idx0 + 3 <= o_hi) ? 1.0f : 0.0f;

    // gaussian taps (sigma=1.5, ksize=3); constant-folded
    const float e  = expf(-1.0f / 4.5f);
    const float g1 = 1.0f / (1.0f + 2.0f * e);
    const float g0 = e * g1;

    const int am = ((lane - 1) & 63) << 2;   // prev-lane bpermute addr
    const int ap = ((lane + 1) & 63) << 2;   // next-lane bpermute addr

    const size_t base = (size_t)b * Wd * ROW + (size_t)idx0;

#define BPERM(A, V) __int_as_float(__builtin_amdgcn_ds_bpermute((A), __float_as_int(V)))

    // row sums from preloaded registers: R = filt_h(d), Q = filt_h(d^2)
#define ROWSUMS_REG(x4, y4, Rr, Qq)                                            \
    {                                                                          \
        float4 d;                                                              \
        d.x = x4.x - y4.x; d.y = x4.y - y4.y;                                  \
        d.z = x4.z - y4.z; d.w = x4.w - y4.w;                                  \
        float pm1 = BPERM(am, d.y), pm2 = BPERM(am, d.z), pm3 = BPERM(am, d.w);\
        float np0 = BPERM(ap, d.x), np1 = BPERM(ap, d.y), np2 = BPERM(ap, d.z);\
        float4 dm, dp;                                                         \
        dm.x = pm1; dm.y = pm2; dm.z = pm3; dm.w = d.x;                        \
        dp.x = d.w; dp.y = np0; dp.z = np1; dp.w = np2;                        \
        Rr.x = fmaf(g0, dm.x + dp.x, g1 * d.x);                                \
        Rr.y = fmaf(g0, dm.y + dp.y, g1 * d.y);                                \
        Rr.z = fmaf(g0, dm.z + dp.z, g1 * d.z);                                \
        Rr.w = fmaf(g0, dm.w + dp.w, g1 * d.w);                                \
        Qq.x = fmaf(g0, fmaf(dp.x, dp.x, dm.x * dm.x), g1 * (d.x * d.x));      \
        Qq.y = fmaf(g0, fmaf(dp.y, dp.y, dm.y * dm.y), g1 * (d.y * d.y));      \
        Qq.z = fmaf(g0, fmaf(dp.z, dp.z, dm.z * dm.z), g1 * (d.z * d.z));      \
        Qq.w = fmaf(g0, fmaf(dp.w, dp.w, dm.w * dm.w), g1 * (d.w * d.w));      \
    }

    float4 R0, R1, Q0, Q1;
    float4 xc, yc;
    size_t off = base + (size_t)(w0 - 1) * ROW;
    {
        // prologue: rows w0-1, w0 direct; row w0+1 preloaded into (xc,yc)
        float4 xa = *reinterpret_cast<const float4*>(X + off);
        float4 ya = *reinterpret_cast<const float4*>(Y + off);
        float4 xb = *reinterpret_cast<const float4*>(X + off + ROW);
        float4 yb = *reinterpret_cast<const float4*>(Y + off + ROW);
        xc = *reinterpret_cast<const float4*>(X + off + 2 * ROW);
        yc = *reinterpret_cast<const float4*>(Y + off + 2 * ROW);
        ROWSUMS_REG(xa, ya, R0, Q0);
        ROWSUMS_REG(xb, yb, R1, Q1);
    }
    off += 3 * (size_t)ROW;   // next row to fetch = w0+2

    float4 acc = {0.0f, 0.0f, 0.0f, 0.0f};
    #pragma unroll 2
    for (int i = 0; i < wn; ++i, off += ROW) {
        // issue next row's loads BEFORE consuming current row (explicit prefetch)
        float4 xn, yn;
        if (i + 1 < wn) {
            xn = *reinterpret_cast<const float4*>(X + off);
            yn = *reinterpret_cast<const float4*>(Y + off);
        }

        float4 R2, Q2;
        ROWSUMS_REG(xc, yc, R2, Q2);

        float4 S1, S2;
        S1.x = fmaf(g0, R0.x + R2.x, g1 * R1.x);
        S1.y = fmaf(g0, R0.y + R2.y, g1 * R1.y);
        S1.z = fmaf(g0, R0.z + R2.z, g1 * R1.z);
        S1.w = fmaf(g0, R0.w + R2.w, g1 * R1.w);
        S2.x = fmaf(g0, Q0.x + Q2.x, g1 * Q1.x);
        S2.y = fmaf(g0, Q0.y + Q2.y, g1 * Q1.y);
        S2.z = fmaf(g0, Q0.z + Q2.z, g1 * Q1.z);
        S2.w = fmaf(g0, Q0.w + Q2.w, g1 * Q1.w);

        acc.x = fmaf(msk.x, fmaf(-S1.x, S1.x, S2.x), acc.x);
        acc.y = fmaf(msk.y, fmaf(-S1.y, S1.y, S2.y), acc.y);
        acc.z = fmaf(msk.z, fmaf(-S1.z, S1.z, S2.z), acc.z);
        acc.w = fmaf(msk.w, fmaf(-S1.w, S1.w, S2.w), acc.w);

        R0 = R1; R1 = R2;
        Q0 = Q1; Q1 = Q2;
        xc = xn; yc = yn;
    }
#undef ROWSUMS_REG
#undef BPERM

    float a = (acc.x + acc.y) + (acc.z + acc.w);

    // deterministic reduction: wave shuffle then LDS
    #pragma unroll
    for (int o = 32; o > 0; o >>= 1) a += __shfl_down(a, o, 64);

    __shared__ float sdata[BLOCK / 64];
    if (lane == 0) sdata[widx] = a;
    __syncthreads();
    if (threadIdx.x == 0) {
        float sum = 0.0f;
        #pragma unroll
        for (int i = 0; i < BLOCK / 64; ++i) sum += sdata[i];
        partial[blockIdx.x] = sum;
    }
}

__global__ __launch_bounds__(BLOCK) void reduce_kernel(
    const float* __restrict__ partial,
    float* __restrict__ out)
{
    float acc = 0.0f;
    for (int i = threadIdx.x; i < NBLK; i += BLOCK) acc += partial[i];

    #pragma unroll
    for (int o = 32; o > 0; o >>= 1) acc += __shfl_down(acc, o, 64);

    __shared__ float sdata[BLOCK / 64];
    const int lane = threadIdx.x & 63;
    const int wid  = threadIdx.x >> 6;
    if (lane == 0) sdata[wid] = acc;
    __syncthreads();
    if (threadIdx.x == 0) {
        float s = 0.0f;
        #pragma unroll
        for (int i = 0; i < BLOCK / 64; ++i) s += sdata[i];
        out[0] = s * (1.0f / ((float)NOUTc * (float)NOUTc * (float)Cd));
    }
}

extern "C" void kernel_launch(void* const* d_in, const int* in_sizes, int n_in,
                              void* d_out, int out_size, void* d_ws, size_t ws_size,
                              hipStream_t stream) {
    const float* X = (const float*)d_in[0];
    const float* Y = (const float*)d_in[1];
    float* out     = (float*)d_out;
    float* partial = (float*)d_ws;   // NBLK floats

    locvar_kernel<<<NBLK, BLOCK, 0, stream>>>(X, Y, partial);
    reduce_kernel<<<1, BLOCK, 0, stream>>>(partial, out);
}

// Round 5
// 40.991 us; speedup vs baseline: 1.1019x; 1.0920x over previous
//
#include <hip/hip_runtime.h>

// X,Y: [32,3,512,512] f32 reinterpreted flat as NHWC [32][512][512][3].
// loss = sum_b mean_{crop} [ filt(d^2) - filt(d)^2 ],  d = X - Y,
// filt = separable 3x3 gaussian (sigma=1.5): taps [g0, g1, g0].
// Crop [5:-5] => reflect padding never exercised.
// hc = h*3+c flat contiguous index in [0,1536); outputs hc in [15,1520].
//
// Round-5 structure: one wave owns (b, hc-half, w-band of 16 rows) and per row
// sweeps 3 (half0) or 4 (half1) ADJACENT masked 256-float windows -> each wave
// reads ~3 KB contiguous per row step (vs 1 KB before) for DRAM row-buffer
// locality. Exclusive output partition: half0 = 3x246 covering [15,752],
// half1 = 4x192 covering [753,1520].

constexpr int ROW   = 1536;           // floats per w-row
constexpr int IMG   = 512 * ROW;      // floats per image
constexpr int BLOCK = 256;
constexpr int CH    = 16;             // output rows per band (last band: 6)
constexpr int NBLK  = 32 * 2 * 8;     // b * half * q = 512 blocks (4 waves each)

__device__ __forceinline__ float bperm(int addr, float v) {
    return __int_as_float(__builtin_amdgcn_ds_bpermute(addr, __float_as_int(v)));
}

__global__ __launch_bounds__(BLOCK, 2) void locvar_kernel(
    const float* __restrict__ X,
    const float* __restrict__ Y,
    float* __restrict__ partial)
{
    const int lane = threadIdx.x & 63;
    const int widx = threadIdx.x >> 6;
    const int blk  = blockIdx.x;
    const int q    = blk & 7;
    const int half = (blk >> 3) & 1;
    const int b    = blk >> 4;

    const int band = q * 4 + widx;           // 0..31 (adjacent waves share halo rows)
    const int w0   = 5 + CH * band;
    const int wn   = min(CH, 507 - w0);      // 16, last band 6 (always even)

    const int nw   = 3 + half;               // windows this wave
    const int HLO  = half ? 753 : 15;
    const int OUTW = half ? 192 : 246;

    // gaussian taps (sigma=1.5, ksize=3); constant-folded
    const float e  = expf(-1.0f / 4.5f);
    const float g1 = 1.0f / (1.0f + 2.0f * e);
    const float g0 = e * g1;

    const int am = ((lane - 1) & 63) << 2;   // prev-lane bpermute addr
    const int ap = ((lane + 1) & 63) << 2;   // next-lane bpermute addr

    // per-window lane base + exclusive output masks
    int gbase[4];
    float4 msk[4];
    #pragma unroll
    for (int j = 0; j < 4; ++j) {
        const int o_lo = HLO + OUTW * j;
        const int o_hi = o_lo + OUTW - 1;
        const int s    = (o_lo - 3) & ~3;    // 16B-aligned staged start
        const int idx0 = s + 4 * lane;
        gbase[j] = b * IMG + idx0;
        msk[j].x = (idx0 + 0 >= o_lo && idx0 + 0 <= o_hi) ? 1.0f : 0.0f;
        msk[j].y = (idx0 + 1 >= o_lo && idx0 + 1 <= o_hi) ? 1.0f : 0.0f;
        msk[j].z = (idx0 + 2 >= o_lo && idx0 + 2 <= o_hi) ? 1.0f : 0.0f;
        msk[j].w = (idx0 + 3 >= o_lo && idx0 + 3 <= o_hi) ? 1.0f : 0.0f;
    }

    float4 xa[4], ya[4], xb[4], yb[4];
    float4 R0[4], R1[4], Q0[4], Q1[4];
    float4 acc = {0.0f, 0.0f, 0.0f, 0.0f};

#define LOADROW(DX, DY, R)                                                      \
    {                                                                           \
        const int ro = (R) * ROW;                                               \
        _Pragma("unroll")                                                       \
        for (int j = 0; j < 4; ++j) if (j < nw) {                               \
            DX[j] = *reinterpret_cast<const float4*>(X + gbase[j] + ro);        \
            DY[j] = *reinterpret_cast<const float4*>(Y + gbase[j] + ro);        \
        }                                                                       \
    }

    // R = filt_h(d), Q = filt_h(d^2) for one row, all windows
#define ROWSUMS(SX, SY, RA, QA)                                                 \
    {                                                                           \
        _Pragma("unroll")                                                       \
        for (int j = 0; j < 4; ++j) if (j < nw) {                               \
            float4 d;                                                           \
            d.x = SX[j].x - SY[j].x; d.y = SX[j].y - SY[j].y;                   \
            d.z = SX[j].z - SY[j].z; d.w = SX[j].w - SY[j].w;                   \
            float pm1 = bperm(am, d.y), pm2 = bperm(am, d.z),                   \
                  pm3 = bperm(am, d.w);                                         \
            float np0 = bperm(ap, d.x), np1 = bperm(ap, d.y),                   \
                  np2 = bperm(ap, d.z);                                         \
            float4 dm, dp;                                                      \
            dm.x = pm1; dm.y = pm2; dm.z = pm3; dm.w = d.x;                     \
            dp.x = d.w; dp.y = np0; dp.z = np1; dp.w = np2;                     \
            RA[j].x = fmaf(g0, dm.x + dp.x, g1 * d.x);                          \
            RA[j].y = fmaf(g0, dm.y + dp.y, g1 * d.y);                          \
            RA[j].z = fmaf(g0, dm.z + dp.z, g1 * d.z);                          \
            RA[j].w = fmaf(g0, dm.w + dp.w, g1 * d.w);                          \
            QA[j].x = fmaf(g0, fmaf(dp.x, dp.x, dm.x * dm.x), g1 * (d.x * d.x));\
            QA[j].y = fmaf(g0, fmaf(dp.y, dp.y, dm.y * dm.y), g1 * (d.y * d.y));\
            QA[j].z = fmaf(g0, fmaf(dp.z, dp.z, dm.z * dm.z), g1 * (d.z * d.z));\
            QA[j].w = fmaf(g0, fmaf(dp.w, dp.w, dm.w * dm.w), g1 * (d.w * d.w));\
        }                                                                       \
    }

    // consume one row (in SX/SY), produce output, shift state, reload SX/SY
#define PHASE(SX, SY, RNEXT)                                                    \
    {                                                                           \
        _Pragma("unroll")                                                       \
        for (int j = 0; j < 4; ++j) if (j < nw) {                               \
            float4 d, R2, Q2;                                                   \
            d.x = SX[j].x - SY[j].x; d.y = SX[j].y - SY[j].y;                   \
            d.z = SX[j].z - SY[j].z; d.w = SX[j].w - SY[j].w;                   \
            float pm1 = bperm(am, d.y), pm2 = bperm(am, d.z),                   \
                  pm3 = bperm(am, d.w);                                         \
            float np0 = bperm(ap, d.x), np1 = bperm(ap, d.y),                   \
                  np2 = bperm(ap, d.z);                                         \
            float4 dm, dp;                                                      \
            dm.x = pm1; dm.y = pm2; dm.z = pm3; dm.w = d.x;                     \
            dp.x = d.w; dp.y = np0; dp.z = np1; dp.w = np2;                     \
            R2.x = fmaf(g0, dm.x + dp.x, g1 * d.x);                             \
            R2.y = fmaf(g0, dm.y + dp.y, g1 * d.y);                             \
            R2.z = fmaf(g0, dm.z + dp.z, g1 * d.z);                             \
            R2.w = fmaf(g0, dm.w + dp.w, g1 * d.w);                             \
            Q2.x = fmaf(g0, fmaf(dp.x, dp.x, dm.x * dm.x), g1 * (d.x * d.x));   \
            Q2.y = fmaf(g0, fmaf(dp.y, dp.y, dm.y * dm.y), g1 * (d.y * d.y));   \
            Q2.z = fmaf(g0, fmaf(dp.z, dp.z, dm.z * dm.z), g1 * (d.z * d.z));   \
            Q2.w = fmaf(g0, fmaf(dp.w, dp.w, dm.w * dm.w), g1 * (d.w * d.w));   \
            float4 S1, S2;                                                      \
            S1.x = fmaf(g0, R0[j].x + R2.x, g1 * R1[j].x);                      \
            S1.y = fmaf(g0, R0[j].y + R2.y, g1 * R1[j].y);                      \
            S1.z = fmaf(g0, R0[j].z + R2.z, g1 * R1[j].z);                      \
            S1.w = fmaf(g0, R0[j].w + R2.w, g1 * R1[j].w);                      \
            S2.x = fmaf(g0, Q0[j].x + Q2.x, g1 * Q1[j].x);                      \
            S2.y = fmaf(g0, Q0[j].y + Q2.y, g1 * Q1[j].y);                      \
            S2.z = fmaf(g0, Q0[j].z + Q2.z, g1 * Q1[j].z);                      \
            S2.w = fmaf(g0, Q0[j].w + Q2.w, g1 * Q1[j].w);                      \
            acc.x = fmaf(msk[j].x, fmaf(-S1.x, S1.x, S2.x), acc.x);             \
            acc.y = fmaf(msk[j].y, fmaf(-S1.y, S1.y, S2.y), acc.y);             \
            acc.z = fmaf(msk[j].z, fmaf(-S1.z, S1.z, S2.z), acc.z);             \
            acc.w = fmaf(msk[j].w, fmaf(-S1.w, S1.w, S2.w), acc.w);             \
            R0[j] = R1[j]; R1[j] = R2;                                          \
            Q0[j] = Q1[j]; Q1[j] = Q2;                                          \
        }                                                                       \
        LOADROW(SX, SY, RNEXT);                                                 \
    }

    // prologue: rows w0-1, w0 -> state; rows w0+1, w0+2 in flight
    LOADROW(xa, ya, w0 - 1);
    LOADROW(xb, yb, w0);
    ROWSUMS(xa, ya, R0, Q0);
    LOADROW(xa, ya, w0 + 1);
    ROWSUMS(xb, yb, R1, Q1);
    LOADROW(xb, yb, w0 + 2);

    // main loop: wn is even (16 or 6); row r=w0+1+i gives output at w=r-1
    for (int i = 0; i < wn; i += 2) {
        PHASE(xa, ya, min(w0 + 3 + i, w0 + wn));
        PHASE(xb, yb, min(w0 + 4 + i, w0 + wn));
    }
#undef PHASE
#undef ROWSUMS
#undef LOADROW

    float a = (acc.x + acc.y) + (acc.z + acc.w);

    // deterministic reduction: wave shuffle then LDS
    #pragma unroll
    for (int o = 32; o > 0; o >>= 1) a += __shfl_down(a, o, 64);

    __shared__ float sdata[BLOCK / 64];
    if (lane == 0) sdata[widx] = a;
    __syncthreads();
    if (threadIdx.x == 0) {
        float sum = 0.0f;
        #pragma unroll
        for (int i = 0; i < BLOCK / 64; ++i) sum += sdata[i];
        partial[blockIdx.x] = sum;
    }
}

__global__ __launch_bounds__(BLOCK) void reduce_kernel(
    const float* __restrict__ partial,
    float* __restrict__ out)
{
    float acc = 0.0f;
    for (int i = threadIdx.x; i < NBLK; i += BLOCK) acc += partial[i];

    #pragma unroll
    for (int o = 32; o > 0; o >>= 1) acc += __shfl_down(acc, o, 64);

    __shared__ float sdata[BLOCK / 64];
    const int lane = threadIdx.x & 63;
    const int wid  = threadIdx.x >> 6;
    if (lane == 0) sdata[wid] = acc;
    __syncthreads();
    if (threadIdx.x == 0) {
        float s = 0.0f;
        #pragma unroll
        for (int i = 0; i < BLOCK / 64; ++i) s += sdata[i];
        out[0] = s * (1.0f / (502.0f * 502.0f * 3.0f));
    }
}

extern "C" void kernel_launch(void* const* d_in, const int* in_sizes, int n_in,
                              void* d_out, int out_size, void* d_ws, size_t ws_size,
                              hipStream_t stream) {
    const float* X = (const float*)d_in[0];
    const float* Y = (const float*)d_in[1];
    float* out     = (float*)d_out;
    float* partial = (float*)d_ws;   // NBLK floats = 2 KB scratch

    locvar_kernel<<<NBLK, BLOCK, 0, stream>>>(X, Y, partial);
    reduce_kernel<<<1, BLOCK, 0, stream>>>(partial, out);
}